// Round 2
// baseline (131.855 us; speedup 1.0000x reference)
//
#include <hip/hip_runtime.h>

#define NC      16
#define HW      (512 * 512)
#define NB      8
#define BPB     128                       // blocks per batch
#define NBLK    (NB * BPB)                // 1024 total blocks
#define THREADS 256
#define CHUNK   (HW / BPB)                // 2048 pixels per block
#define VITERS  (CHUNK / (THREADS * 4))   // 2 float4-iterations per thread
#define SMOOTH  1e-5f

// Partials in d_ws, SoA: P[v * NBLK + blk], v in [0,34):
//   v = 0..15  : inter[c]   (for batch b = blk / BPB)
//   v = 16..31 : denom[c]
//   v = 32     : ce partial
//   v = 33     : pen partial
// Every slot is overwritten every launch -> no zeroing, no atomics.
__global__ __launch_bounds__(THREADS, 4) void domino_main(
    const float* __restrict__ logits,   // [B, C, H, W]
    const int*   __restrict__ tgt,      // [B, H, W]
    const float* __restrict__ penalty,  // [C, C] row = target class
    float*       __restrict__ P)
{
    __shared__ float pen_t[NC * NC];    // transposed: pen_t[c*NC + t] = penalty[t*NC + c]
    __shared__ float red[4][34];

    const int tid = threadIdx.x;
    const int b   = blockIdx.x / BPB;
    const int blk = blockIdx.x % BPB;

    if (tid < NC * NC) {
        const int r = tid / NC, c = tid % NC;
        pen_t[c * NC + r] = penalty[tid];
    }
    __syncthreads();

    float inter_acc[NC], denom_acc[NC];
#pragma unroll
    for (int c = 0; c < NC; ++c) { inter_acc[c] = 0.f; denom_acc[c] = 0.f; }
    float ce_acc = 0.f, pen_acc = 0.f;

    const float* ob = logits + (size_t)b * NC * HW;
    const int*   tb = tgt    + (size_t)b * HW;

#pragma unroll
    for (int k = 0; k < VITERS; ++k) {
        const int g   = blk * (CHUNK / 4) + k * THREADS + tid;  // float4 group index
        const int pix = g * 4;

        float4 x[NC];
#pragma unroll
        for (int c = 0; c < NC; ++c)
            x[c] = *(const float4*)(ob + (size_t)c * HW + pix);
        const int4 t4 = *(const int4*)(tb + pix);

        // One pixel = component F of the float4 group, target TT.
        // exp is recomputed in the second pass instead of cached in e[16]
        // -> saves 16 VGPRs (trans pipe is cheap; kernel is memory-bound).
#define PROC(F, TT) do {                                                    \
        const int t = (TT);                                                 \
        float m = -3.402823466e+38f;                                        \
        _Pragma("unroll")                                                   \
        for (int c = 0; c < NC; ++c) m = fmaxf(m, x[c].F);                  \
        float s = 0.f, xt = 0.f;                                            \
        _Pragma("unroll")                                                   \
        for (int c = 0; c < NC; ++c) {                                      \
            s  += __expf(x[c].F - m);                                       \
            xt += (t == c) ? x[c].F : 0.f;                                  \
        }                                                                   \
        const float inv = 1.0f / s;                                         \
        ce_acc += (__logf(s) + m) - xt;                                     \
        float pdot = 0.f;                                                   \
        _Pragma("unroll")                                                   \
        for (int c = 0; c < NC; ++c) {                                      \
            const float p = __expf(x[c].F - m) * inv;                       \
            denom_acc[c] += p + ((t == c) ? 1.f : 0.f);                     \
            inter_acc[c] += (t == c) ? p : 0.f;                             \
            pdot += pen_t[c * NC + t] * p;                                  \
        }                                                                   \
        pen_acc += pdot;                                                    \
    } while (0)

        PROC(x, t4.x);
        PROC(y, t4.y);
        PROC(z, t4.z);
        PROC(w, t4.w);
#undef PROC
    }

    // Intra-wave butterfly reductions (64 lanes).
#pragma unroll
    for (int c = 0; c < NC; ++c) {
#pragma unroll
        for (int off = 32; off; off >>= 1) {
            inter_acc[c] += __shfl_xor(inter_acc[c], off);
            denom_acc[c] += __shfl_xor(denom_acc[c], off);
        }
    }
#pragma unroll
    for (int off = 32; off; off >>= 1) {
        ce_acc  += __shfl_xor(ce_acc,  off);
        pen_acc += __shfl_xor(pen_acc, off);
    }

    const int lane = tid & 63, wid = tid >> 6;
    if (lane == 0) {
#pragma unroll
        for (int c = 0; c < NC; ++c) {
            red[wid][c]      = inter_acc[c];
            red[wid][NC + c] = denom_acc[c];
        }
        red[wid][32] = ce_acc;
        red[wid][33] = pen_acc;
    }
    __syncthreads();

    if (tid < 34) {
        const float v = red[0][tid] + red[1][tid] + red[2][tid] + red[3][tid];
        P[tid * NBLK + blockIdx.x] = v;
    }
}

__global__ __launch_bounds__(128) void domino_final(
    const float* __restrict__ P, float* __restrict__ out)
{
    const int tid = threadIdx.x;            // 128 threads: one per (c,b) dice bin
    const int c = tid >> 3, b = tid & 7;

    float inter = 0.f, denom = 0.f;
    const float4* ip = (const float4*)(P + (size_t)c        * NBLK + b * BPB);
    const float4* dp = (const float4*)(P + (size_t)(NC + c) * NBLK + b * BPB);
#pragma unroll 8
    for (int k = 0; k < BPB / 4; ++k) {
        const float4 a = ip[k]; inter += a.x + a.y + a.z + a.w;
        const float4 d = dp[k]; denom += d.x + d.y + d.z + d.w;
    }
    float dice = 1.0f - (2.0f * inter + SMOOTH) / (denom + SMOOTH);

    float ce = 0.f, pen = 0.f;
    const float4* cp = (const float4*)(P + 32 * NBLK + tid * 8);
    const float4* pp = (const float4*)(P + 33 * NBLK + tid * 8);
#pragma unroll
    for (int k = 0; k < 2; ++k) {
        const float4 a = cp[k]; ce  += a.x + a.y + a.z + a.w;
        const float4 d = pp[k]; pen += d.x + d.y + d.z + d.w;
    }

#pragma unroll
    for (int off = 32; off; off >>= 1) {
        dice += __shfl_xor(dice, off);
        ce   += __shfl_xor(ce,   off);
        pen  += __shfl_xor(pen,  off);
    }
    __shared__ float r[3][2];
    const int lane = tid & 63, wid = tid >> 6;
    if (lane == 0) { r[0][wid] = dice; r[1][wid] = ce; r[2][wid] = pen; }
    __syncthreads();
    if (tid == 0) {
        out[0] = (r[1][0] + r[1][1]) * (1.0f / (8.0f * 262144.0f))
               + (r[0][0] + r[0][1]) * (1.0f / 128.0f)
               + (r[2][0] + r[2][1]) * (1.0f / 8.0f);
    }
}

extern "C" void kernel_launch(void* const* d_in, const int* in_sizes, int n_in,
                              void* d_out, int out_size, void* d_ws, size_t ws_size,
                              hipStream_t stream)
{
    const float* logits = (const float*)d_in[0];   // [8,16,512,512] f32
    const int*   tgt    = (const int*)d_in[1];     // [8,1,512,512] int32
    const float* pen    = (const float*)d_in[2];   // [16,16] f32
    float*       P      = (float*)d_ws;
    float*       out    = (float*)d_out;

    domino_main<<<NBLK, THREADS, 0, stream>>>(logits, tgt, pen, P);
    domino_final<<<1, 128, 0, stream>>>(P, out);
}

// Round 3
// 42.172 us; speedup vs baseline: 3.1266x; 3.1266x over previous
//
#include <hip/hip_runtime.h>

#define NC      16
#define HW      (512 * 512)
#define NB      8
#define BPB     128                       // blocks per batch
#define NBLK    (NB * BPB)                // 1024 total blocks
#define THREADS 256
#define CHUNK   (HW / BPB)                // 2048 pixels per block
#define VITERS  (CHUNK / (THREADS * 2))   // 4 float2-iterations per thread
#define SMOOTH  1e-5f

// Partials in d_ws, SoA: P[v * NBLK + blk], v in [0,34):
//   v = 0..15  : inter[c]   (for batch b = blk / BPB)
//   v = 16..31 : denom[c]
//   v = 32     : ce partial
//   v = 33     : pen partial
// Every slot is overwritten every launch -> no zeroing, no atomics.
//
// VGPR note: round 2 proved __launch_bounds__(256,4) + float4 x[16] spills
// (VGPR clamped to 64, 261 MB scratch writes). Here the register need is cut
// structurally (float2 -> x[16] = 32 VGPR) and the allocator is left free.
__global__ __launch_bounds__(THREADS) void domino_main(
    const float* __restrict__ logits,   // [B, C, H, W]
    const int*   __restrict__ tgt,      // [B, H, W]
    const float* __restrict__ penalty,  // [C, C] row = target class
    float*       __restrict__ P)
{
    __shared__ float pen_t[NC * NC];    // transposed: pen_t[c*NC + t] = penalty[t*NC + c]
    __shared__ float red[4][34];

    const int tid = threadIdx.x;
    const int b   = blockIdx.x / BPB;
    const int blk = blockIdx.x % BPB;

    if (tid < NC * NC) {
        const int r = tid / NC, c = tid % NC;
        pen_t[c * NC + r] = penalty[tid];
    }
    __syncthreads();

    float inter_acc[NC], denom_acc[NC];
#pragma unroll
    for (int c = 0; c < NC; ++c) { inter_acc[c] = 0.f; denom_acc[c] = 0.f; }
    float ce_acc = 0.f, pen_acc = 0.f;

    const float* ob = logits + (size_t)b * NC * HW;
    const int*   tb = tgt    + (size_t)b * HW;

#pragma unroll
    for (int k = 0; k < VITERS; ++k) {
        const int g   = blk * (CHUNK / 2) + k * THREADS + tid;  // float2 group index
        const int pix = g * 2;

        float2 x[NC];
#pragma unroll
        for (int c = 0; c < NC; ++c)
            x[c] = *(const float2*)(ob + (size_t)c * HW + pix);
        const int2 t2 = *(const int2*)(tb + pix);

        // One pixel = component F of the float2 group, target TT.
        // exp recomputed in the 2nd pass (trans pipe ~1.7 us chip-wide, free)
        // so no e[16] array -> keeps VGPR < 128.
#define PROC(F, TT) do {                                                    \
        const int t = (TT);                                                 \
        float m = -3.402823466e+38f;                                        \
        _Pragma("unroll")                                                   \
        for (int c = 0; c < NC; ++c) m = fmaxf(m, x[c].F);                  \
        float s = 0.f, xt = 0.f;                                            \
        _Pragma("unroll")                                                   \
        for (int c = 0; c < NC; ++c) {                                      \
            s  += __expf(x[c].F - m);                                       \
            xt += (t == c) ? x[c].F : 0.f;                                  \
        }                                                                   \
        const float inv = 1.0f / s;                                         \
        ce_acc += (__logf(s) + m) - xt;                                     \
        float pdot = 0.f;                                                   \
        _Pragma("unroll")                                                   \
        for (int c = 0; c < NC; ++c) {                                      \
            const float p = __expf(x[c].F - m) * inv;                       \
            denom_acc[c] += p + ((t == c) ? 1.f : 0.f);                     \
            inter_acc[c] += (t == c) ? p : 0.f;                             \
            pdot += pen_t[c * NC + t] * p;                                  \
        }                                                                   \
        pen_acc += pdot;                                                    \
    } while (0)

        PROC(x, t2.x);
        PROC(y, t2.y);
#undef PROC
    }

    // Intra-wave butterfly reductions (64 lanes).
#pragma unroll
    for (int c = 0; c < NC; ++c) {
#pragma unroll
        for (int off = 32; off; off >>= 1) {
            inter_acc[c] += __shfl_xor(inter_acc[c], off);
            denom_acc[c] += __shfl_xor(denom_acc[c], off);
        }
    }
#pragma unroll
    for (int off = 32; off; off >>= 1) {
        ce_acc  += __shfl_xor(ce_acc,  off);
        pen_acc += __shfl_xor(pen_acc, off);
    }

    const int lane = tid & 63, wid = tid >> 6;
    if (lane == 0) {
#pragma unroll
        for (int c = 0; c < NC; ++c) {
            red[wid][c]      = inter_acc[c];
            red[wid][NC + c] = denom_acc[c];
        }
        red[wid][32] = ce_acc;
        red[wid][33] = pen_acc;
    }
    __syncthreads();

    if (tid < 34) {
        const float v = red[0][tid] + red[1][tid] + red[2][tid] + red[3][tid];
        P[tid * NBLK + blockIdx.x] = v;
    }
}

__global__ __launch_bounds__(128) void domino_final(
    const float* __restrict__ P, float* __restrict__ out)
{
    const int tid = threadIdx.x;            // 128 threads: one per (c,b) dice bin
    const int c = tid >> 3, b = tid & 7;

    float inter = 0.f, denom = 0.f;
    const float4* ip = (const float4*)(P + (size_t)c        * NBLK + b * BPB);
    const float4* dp = (const float4*)(P + (size_t)(NC + c) * NBLK + b * BPB);
#pragma unroll 8
    for (int k = 0; k < BPB / 4; ++k) {
        const float4 a = ip[k]; inter += a.x + a.y + a.z + a.w;
        const float4 d = dp[k]; denom += d.x + d.y + d.z + d.w;
    }
    float dice = 1.0f - (2.0f * inter + SMOOTH) / (denom + SMOOTH);

    float ce = 0.f, pen = 0.f;
    const float4* cp = (const float4*)(P + 32 * NBLK + tid * 8);
    const float4* pp = (const float4*)(P + 33 * NBLK + tid * 8);
#pragma unroll
    for (int k = 0; k < 2; ++k) {
        const float4 a = cp[k]; ce  += a.x + a.y + a.z + a.w;
        const float4 d = pp[k]; pen += d.x + d.y + d.z + d.w;
    }

#pragma unroll
    for (int off = 32; off; off >>= 1) {
        dice += __shfl_xor(dice, off);
        ce   += __shfl_xor(ce,   off);
        pen  += __shfl_xor(pen,  off);
    }
    __shared__ float r[3][2];
    const int lane = tid & 63, wid = tid >> 6;
    if (lane == 0) { r[0][wid] = dice; r[1][wid] = ce; r[2][wid] = pen; }
    __syncthreads();
    if (tid == 0) {
        out[0] = (r[1][0] + r[1][1]) * (1.0f / (8.0f * 262144.0f))
               + (r[0][0] + r[0][1]) * (1.0f / 128.0f)
               + (r[2][0] + r[2][1]) * (1.0f / 8.0f);
    }
}

extern "C" void kernel_launch(void* const* d_in, const int* in_sizes, int n_in,
                              void* d_out, int out_size, void* d_ws, size_t ws_size,
                              hipStream_t stream)
{
    const float* logits = (const float*)d_in[0];   // [8,16,512,512] f32
    const int*   tgt    = (const int*)d_in[1];     // [8,1,512,512] int32
    const float* pen    = (const float*)d_in[2];   // [16,16] f32
    float*       P      = (float*)d_ws;
    float*       out    = (float*)d_out;

    domino_main<<<NBLK, THREADS, 0, stream>>>(logits, tgt, pen, P);
    domino_final<<<1, 128, 0, stream>>>(P, out);
}